// Round 5
// baseline (1322.308 us; speedup 1.0000x reference)
//
#include <hip/hip_runtime.h>
#include <stdint.h>

#define NSEG 2048
#define NTOT 1048576
#define CAP  624            // max nodes per segment held in LDS (multiple of 16)
#define BLK  1024
#define JH   5              // phase-A half length (MAX_RT = 10)
#define H_BYTES (CAP * 256)                      // bf16 h[CAP][128]
// LDS: h | cs[2][128] | lbias[128] | wbuf[512]
#define CS_OFF    H_BYTES
#define LBIAS_OFF (H_BYTES + 1024)
#define WBUF_OFF  (H_BYTES + 1024 + 512)
#define LDS_BYTES (H_BYTES + 1024 + 512 + 2048)  // 163328 <= 163840

typedef __bf16 bf16x8 __attribute__((ext_vector_type(8)));
typedef __bf16 bf16x4 __attribute__((ext_vector_type(4)));
typedef float  f32x4  __attribute__((ext_vector_type(4)));

__device__ __forceinline__ float leaky(float v) { return fmaxf(v, 0.01f * v); }
// swizzled byte address into LDS h tile: row pitch 256B, XOR bits 4-6 by row&7
__device__ __forceinline__ uint32_t haddr(int row, int bytecol) {
    return ((uint32_t)row * 256u + (uint32_t)bytecol) ^ (((uint32_t)row & 7u) << 4);
}

// offs[t] = lower_bound(seg, t): segment t occupies [offs[t], offs[t+1])
__global__ void seg_offsets_kernel(const int* __restrict__ seg, int* __restrict__ offs) {
    int t = blockIdx.x * blockDim.x + threadIdx.x;
    if (t > NSEG) return;
    int lo = 0, hi = NTOT;
    while (lo < hi) { int mid = (lo + hi) >> 1; if (seg[mid] < t) lo = mid + 1; else hi = mid; }
    offs[t] = lo;
}

// Wt[m][n][k] = bf16(W_m[k][n])  (transposed so k is contiguous for fragment loads)
__global__ void wconv_kernel(const float* __restrict__ W1b, const float* __restrict__ W2,
                             const float* __restrict__ W3,  const float* __restrict__ W4,
                             const float* __restrict__ W5,  __bf16* __restrict__ wt) {
    int idx = blockIdx.x * blockDim.x + threadIdx.x;   // 0 .. 5*16384-1
    int m = idx >> 14, e = idx & 16383;
    int nn = e >> 7, kk = e & 127;
    const float* W = (m == 0) ? W1b : (m == 1) ? W2 : (m == 2) ? W3 : (m == 3) ? W4 : W5;
    wt[idx] = (__bf16)W[kk * 128 + nn];
}

extern __shared__ char smem[];

__global__ __launch_bounds__(BLK)
void __attribute__((amdgpu_waves_per_eu(4, 4)))    // pin: 4 waves/EU = our real occupancy
fused_pflow(
    const float* __restrict__ feat, const int* __restrict__ offs,
    const __bf16* __restrict__ wt5,
    const float* __restrict__ W1a, const float* __restrict__ b1a,
    const float* __restrict__ Wl0, const float* __restrict__ bl0,   // W1b,b1b
    const float* __restrict__ Wl1, const float* __restrict__ bl1,   // W2,b2
    const float* __restrict__ Wl2, const float* __restrict__ bl2,
    const float* __restrict__ Wl3, const float* __restrict__ bl3,
    const float* __restrict__ Wl4, const float* __restrict__ bl4,
    const float* __restrict__ Wo1, const float* __restrict__ bo1,
    const float* __restrict__ Wo2, const float* __restrict__ bo2,
    float* __restrict__ out)
{
    const int s    = blockIdx.x;
    const int tid  = threadIdx.x;
    const int lane = tid & 63;
    const int wave = tid >> 6;     // 0..15
    const int lm   = lane & 15;    // MFMA node lane
    const int lq   = lane >> 4;    // C row-quad
    const int cg   = wave & 3;     // channel group: ct = cg*2 + {0,1}
    const int rg   = wave >> 2;    // row group: rt = rg + 4*j

    char*  sm    = smem;
    float* cs0   = (float*)(sm + CS_OFF);      // column-sum ping
    float* cs1   = cs0 + 128;                  // column-sum pong
    float* lbias = (float*)(sm + LBIAS_OFF);   // folded bias of current layer
    float* wbuf  = (float*)(sm + WBUF_OFF);    // layer-1a W+b, [ch][4]

    const int g0 = offs[s];
    int n = offs[s + 1] - g0;
    n = n < CAP ? n : CAP;

    // wbuf[ch*4+j] = {W1a[0][ch], W1a[1][ch], W1a[2][ch], b1a[ch]}
    if (tid < 512) {
        int ch = tid >> 2, j = tid & 3;
        wbuf[tid] = (j < 3) ? W1a[j * 128 + ch] : b1a[ch];
    }
    if (tid < 256) cs0[tid] = 0.f;             // zero both cs buffers (contiguous)
    __syncthreads();

    // ---- layer 1a: h = leaky(feat @ W1a + b1a); 2 threads per node ----
    for (int idx = tid; idx < n * 2; idx += BLK) {
        const int i = idx >> 1, half = idx & 1;
        float f0 = feat[(g0 + i) * 3 + 0];
        float f1 = feat[(g0 + i) * 3 + 1];
        float f2 = feat[(g0 + i) * 3 + 2];
        #pragma unroll
        for (int cc = 0; cc < 8; ++cc) {
            const int c0 = half * 64 + cc * 8;
            bf16x8 pk;
            #pragma unroll
            for (int j = 0; j < 8; ++j) {
                const f32x4 w = *(const f32x4*)&wbuf[(c0 + j) * 4];
                pk[j] = (__bf16)leaky(fmaf(f0, w[0], fmaf(f1, w[1], fmaf(f2, w[2], w[3]))));
            }
            *(bf16x8*)(sm + haddr(i, c0 * 2)) = pk;
        }
    }

    const int   ntiles = (n + 15) >> 4;
    const float inv_n  = 1.f / (float)(n > 1 ? n : 1);
    const int   ct0    = cg * 2;
    const int   cnt    = (ntiles > rg) ? ((ntiles - rg + 3) >> 2) : 0;  // wave-uniform, <= 10

    // ---- 5 GEMM layers: h = leaky(h @ W + b'), b' = b + mean_prev @ W ----
    for (int L = 0; L < 5; ++L) {
        __syncthreads();                       // h stable (B2 of prev layer), atomics done
        float* csCur  = (L & 1) ? cs1 : cs0;
        float* csPrev = (L & 1) ? cs0 : cs1;
        if (L == 0) {
            if (tid < 128) lbias[tid] = bl0[tid];
        } else {
            // fold residual mean into bias: lbias = b + inv_n * (csPrev @ W), f32
            const float* Wc = (L == 1) ? Wl1 : (L == 2) ? Wl2 : (L == 3) ? Wl3 : Wl4;
            const float* bc = (L == 1) ? bl1 : (L == 2) ? bl2 : (L == 3) ? bl3 : bl4;
            const int ch = tid >> 3, q = tid & 7;   // 8 partials of 16 k each
            float sacc = 0.f;
            #pragma unroll
            for (int i = 0; i < 16; ++i) {
                const int k = q * 16 + i;
                sacc = fmaf(csPrev[k], Wc[k * 128 + ch], sacc);
            }
            sacc += __shfl_xor(sacc, 1);
            sacc += __shfl_xor(sacc, 2);
            sacc += __shfl_xor(sacc, 4);
            if (q == 0) lbias[ch] = fmaf(inv_n, sacc, bc[ch]);
            if (tid < 128) csCur[tid] = 0.f;
        }
        __syncthreads();                       // lbias ready, csCur zeroed

        // A = W^T fragments for this wave's 2 channel tiles (32 VGPR)
        const __bf16* wt = wt5 + L * 16384;
        bf16x8 afrag[2][4];
        #pragma unroll
        for (int c = 0; c < 2; ++c)
            #pragma unroll
            for (int ks = 0; ks < 4; ++ks)
                afrag[c][ks] = *(const bf16x8*)(wt + ((ct0 + c) * 16 + lm) * 128 + ks * 32 + lq * 8);
        f32x4 lbreg[2];
        #pragma unroll
        for (int c = 0; c < 2; ++c)
            lbreg[c] = *(const f32x4*)&lbias[(ct0 + c) * 16 + lq * 4];

        float csum0[4] = {}, csum1[4] = {};

        // ---- phase A1: tiles j=0..4 -> hregA ----
        bf16x4 hregA[JH][2];
        #pragma unroll
        for (int j = 0; j < JH; ++j) {
            if (j < cnt) {
                const int node = (rg + 4 * j) * 16 + lm;
                bf16x8 bfrag[4];
                #pragma unroll
                for (int ks = 0; ks < 4; ++ks)
                    bfrag[ks] = *(const bf16x8*)(sm + haddr(node, ks * 64 + lq * 16));
                f32x4 acc0 = lbreg[0], acc1 = lbreg[1];
                #pragma unroll
                for (int ks = 0; ks < 4; ++ks) {
                    acc0 = __builtin_amdgcn_mfma_f32_16x16x32_bf16(afrag[0][ks], bfrag[ks], acc0, 0, 0, 0);
                    acc1 = __builtin_amdgcn_mfma_f32_16x16x32_bf16(afrag[1][ks], bfrag[ks], acc1, 0, 0, 0);
                }
                #pragma unroll
                for (int i = 0; i < 4; ++i) {
                    hregA[j][0][i] = (__bf16)leaky(acc0[i]);
                    hregA[j][1][i] = (__bf16)leaky(acc1[i]);
                }
            }
            __builtin_amdgcn_sched_barrier(0);  // cap cross-iter hoisting (reg budget)
        }
        __syncthreads();                       // all A1 reads done

        // ---- phase B1 (write tiles 0..4) then A2 (read tiles 5..9, disjoint rows) ----
        #pragma unroll
        for (int j = 0; j < JH; ++j) {
            if (j < cnt) {
                const int node = (rg + 4 * j) * 16 + lm;
                if (node < n) {
                    *(bf16x4*)(sm + haddr(node, (ct0 * 16 + lq * 4) * 2))       = hregA[j][0];
                    *(bf16x4*)(sm + haddr(node, ((ct0 + 1) * 16 + lq * 4) * 2)) = hregA[j][1];
                    #pragma unroll
                    for (int i = 0; i < 4; ++i) {
                        csum0[i] += (float)hregA[j][0][i];
                        csum1[i] += (float)hregA[j][1][i];
                    }
                }
            }
        }
        __builtin_amdgcn_sched_barrier(0);      // B1 emitted before A2 (reg reuse)
        bf16x4 hregB[JH][2];
        #pragma unroll
        for (int j = JH; j < 2 * JH; ++j) {
            if (j < cnt) {
                const int node = (rg + 4 * j) * 16 + lm;
                bf16x8 bfrag[4];
                #pragma unroll
                for (int ks = 0; ks < 4; ++ks)
                    bfrag[ks] = *(const bf16x8*)(sm + haddr(node, ks * 64 + lq * 16));
                f32x4 acc0 = lbreg[0], acc1 = lbreg[1];
                #pragma unroll
                for (int ks = 0; ks < 4; ++ks) {
                    acc0 = __builtin_amdgcn_mfma_f32_16x16x32_bf16(afrag[0][ks], bfrag[ks], acc0, 0, 0, 0);
                    acc1 = __builtin_amdgcn_mfma_f32_16x16x32_bf16(afrag[1][ks], bfrag[ks], acc1, 0, 0, 0);
                }
                #pragma unroll
                for (int i = 0; i < 4; ++i) {
                    hregB[j - JH][0][i] = (__bf16)leaky(acc0[i]);
                    hregB[j - JH][1][i] = (__bf16)leaky(acc1[i]);
                }
            }
            __builtin_amdgcn_sched_barrier(0);
        }
        __syncthreads();                       // all A2 reads done

        // ---- phase B2: write tiles 5..9 + finish column sums ----
        #pragma unroll
        for (int j = JH; j < 2 * JH; ++j) {
            if (j < cnt) {
                const int node = (rg + 4 * j) * 16 + lm;
                if (node < n) {
                    *(bf16x4*)(sm + haddr(node, (ct0 * 16 + lq * 4) * 2))       = hregB[j - JH][0];
                    *(bf16x4*)(sm + haddr(node, ((ct0 + 1) * 16 + lq * 4) * 2)) = hregB[j - JH][1];
                    #pragma unroll
                    for (int i = 0; i < 4; ++i) {
                        csum0[i] += (float)hregB[j - JH][0][i];
                        csum1[i] += (float)hregB[j - JH][1][i];
                    }
                }
            }
        }
        #pragma unroll
        for (int i = 0; i < 4; ++i) {
            float v0 = csum0[i], v1 = csum1[i];
            v0 += __shfl_xor(v0, 1); v0 += __shfl_xor(v0, 2);
            v0 += __shfl_xor(v0, 4); v0 += __shfl_xor(v0, 8);
            v1 += __shfl_xor(v1, 1); v1 += __shfl_xor(v1, 2);
            v1 += __shfl_xor(v1, 4); v1 += __shfl_xor(v1, 8);
            if (lm == 0) {
                atomicAdd(&csCur[ct0 * 16 + lq * 4 + i], v0);
                atomicAdd(&csCur[(ct0 + 1) * 16 + lq * 4 + i], v1);
            }
        }
    }
    __syncthreads();                           // layer-5 atomics into cs0 done

    // ---- output head: g = cs0*inv_n; e = leaky(g@Wo1+bo1)@Wo2 + bo2 ----
    if (wave == 0) {
        float a = bo1[lane];                   // 64 lanes = 64 hidden units
        for (int k = 0; k < 128; ++k)
            a = fmaf(cs0[k] * inv_n, Wo1[k * 64 + lane], a);
        a = leaky(a);
        float e = a * Wo2[lane];
        e += __shfl_xor(e, 32); e += __shfl_xor(e, 16); e += __shfl_xor(e, 8);
        e += __shfl_xor(e, 4);  e += __shfl_xor(e, 2);  e += __shfl_xor(e, 1);
        if (lane == 0) out[s] = e + bo2[0];
    }
}

extern "C" void kernel_launch(void* const* d_in, const int* in_sizes, int n_in,
                              void* d_out, int out_size, void* d_ws, size_t ws_size,
                              hipStream_t stream) {
    (void)in_sizes; (void)n_in; (void)out_size; (void)ws_size;
    const float* feat = (const float*)d_in[0];
    const int*   seg  = (const int*)d_in[1];
    const float* W1a  = (const float*)d_in[2];
    const float* b1a  = (const float*)d_in[3];
    const float* W1b  = (const float*)d_in[4];
    const float* b1b  = (const float*)d_in[5];
    const float* W2   = (const float*)d_in[6];
    const float* b2   = (const float*)d_in[7];
    const float* W3   = (const float*)d_in[8];
    const float* b3   = (const float*)d_in[9];
    const float* W4   = (const float*)d_in[10];
    const float* b4   = (const float*)d_in[11];
    const float* W5   = (const float*)d_in[12];
    const float* b5   = (const float*)d_in[13];
    const float* Wo1  = (const float*)d_in[14];
    const float* bo1  = (const float*)d_in[15];
    const float* Wo2  = (const float*)d_in[16];
    const float* bo2  = (const float*)d_in[17];
    float* out = (float*)d_out;

    __bf16* wt = (__bf16*)d_ws;                                   // 5*16384 bf16
    int* offs = (int*)((char*)d_ws + 5 * 16384 * sizeof(__bf16));

    seg_offsets_kernel<<<(NSEG + 256) / 256, 256, 0, stream>>>(seg, offs);
    wconv_kernel<<<(5 * 16384) / 256, 256, 0, stream>>>(W1b, W2, W3, W4, W5, wt);

    hipFuncSetAttribute((const void*)fused_pflow,
                        hipFuncAttributeMaxDynamicSharedMemorySize, LDS_BYTES);
    fused_pflow<<<NSEG, BLK, LDS_BYTES, stream>>>(feat, offs, wt, W1a, b1a,
                                                  W1b, b1b, W2, b2, W3, b3,
                                                  W4, b4, W5, b5,
                                                  Wo1, bo1, Wo2, bo2, out);
}

// Round 6
// 1086.648 us; speedup vs baseline: 1.2169x; 1.2169x over previous
//
#include <hip/hip_runtime.h>
#include <stdint.h>

#define NSEG 2048
#define NTOT 1048576
#define CAP  624            // max nodes per segment held in LDS (multiple of 16)
#define BLK  768            // 12 waves = 3 waves/SIMD, 170-reg unified budget
#define JH1  7              // phase half 1: tiles j=0..6
#define JH2  6              // phase half 2: tiles j=7..12  (max cnt = 13)
#define H_BYTES (CAP * 256)                      // bf16 h[CAP][128]
// LDS: h | cs[2][128] | lbias[128] | wbuf[512]
#define CS_OFF    H_BYTES
#define LBIAS_OFF (H_BYTES + 1024)
#define WBUF_OFF  (H_BYTES + 1024 + 512)
#define LDS_BYTES (H_BYTES + 1024 + 512 + 2048)  // 163328 <= 163840

typedef __bf16 bf16x8 __attribute__((ext_vector_type(8)));
typedef __bf16 bf16x4 __attribute__((ext_vector_type(4)));
typedef float  f32x4  __attribute__((ext_vector_type(4)));

__device__ __forceinline__ float leaky(float v) { return fmaxf(v, 0.01f * v); }
// swizzled byte address into LDS h tile: row pitch 256B, XOR bits 4-6 by row&7
__device__ __forceinline__ uint32_t haddr(int row, int bytecol) {
    return ((uint32_t)row * 256u + (uint32_t)bytecol) ^ (((uint32_t)row & 7u) << 4);
}

// offs[t] = lower_bound(seg, t): segment t occupies [offs[t], offs[t+1])
__global__ void seg_offsets_kernel(const int* __restrict__ seg, int* __restrict__ offs) {
    int t = blockIdx.x * blockDim.x + threadIdx.x;
    if (t > NSEG) return;
    int lo = 0, hi = NTOT;
    while (lo < hi) { int mid = (lo + hi) >> 1; if (seg[mid] < t) lo = mid + 1; else hi = mid; }
    offs[t] = lo;
}

// Wt[m][n][k] = bf16(W_m[k][n])  (transposed so k is contiguous for fragment loads)
__global__ void wconv_kernel(const float* __restrict__ W1b, const float* __restrict__ W2,
                             const float* __restrict__ W3,  const float* __restrict__ W4,
                             const float* __restrict__ W5,  __bf16* __restrict__ wt) {
    int idx = blockIdx.x * blockDim.x + threadIdx.x;   // 0 .. 5*16384-1
    int m = idx >> 14, e = idx & 16383;
    int nn = e >> 7, kk = e & 127;
    const float* W = (m == 0) ? W1b : (m == 1) ? W2 : (m == 2) ? W3 : (m == 3) ? W4 : W5;
    wt[idx] = (__bf16)W[kk * 128 + nn];
}

extern __shared__ char smem[];

// NOTE: this exact attribute form (plain __global__ void, both attrs together)
// is the only one that has produced a correct VGPR allocation (round 3).
__global__ void __attribute__((amdgpu_flat_work_group_size(BLK, BLK),
                               amdgpu_waves_per_eu(3, 3)))
fused_pflow(
    const float* __restrict__ feat, const int* __restrict__ offs,
    const __bf16* __restrict__ wt5,
    const float* __restrict__ W1a, const float* __restrict__ b1a,
    const float* __restrict__ Wl0, const float* __restrict__ bl0,   // W1b,b1b
    const float* __restrict__ Wl1, const float* __restrict__ bl1,   // W2,b2
    const float* __restrict__ Wl2, const float* __restrict__ bl2,
    const float* __restrict__ Wl3, const float* __restrict__ bl3,
    const float* __restrict__ Wl4, const float* __restrict__ bl4,
    const float* __restrict__ Wo1, const float* __restrict__ bo1,
    const float* __restrict__ Wo2, const float* __restrict__ bo2,
    float* __restrict__ out)
{
    const int s    = blockIdx.x;
    const int tid  = threadIdx.x;
    const int lane = tid & 63;
    const int wave = tid >> 6;     // 0..11
    const int lm   = lane & 15;    // MFMA node lane
    const int lq   = lane >> 4;    // C row-quad
    const int cg   = wave & 3;     // channel group: ct = cg*2 + {0,1}
    const int rg   = wave >> 2;    // row group 0..2: rt = rg + 3*j

    char*  sm    = smem;
    float* cs0   = (float*)(sm + CS_OFF);      // column-sum ping
    float* cs1   = cs0 + 128;                  // column-sum pong
    float* lbias = (float*)(sm + LBIAS_OFF);   // folded bias of current layer
    float* wbuf  = (float*)(sm + WBUF_OFF);    // layer-1a W+b, [ch][4]

    const int g0 = offs[s];
    int n = offs[s + 1] - g0;
    n = n < CAP ? n : CAP;

    // wbuf[ch*4+j] = {W1a[0][ch], W1a[1][ch], W1a[2][ch], b1a[ch]}
    if (tid < 512) {
        int ch = tid >> 2, j = tid & 3;
        wbuf[tid] = (j < 3) ? W1a[j * 128 + ch] : b1a[ch];
    }
    if (tid < 256) cs0[tid] = 0.f;             // zero both cs buffers (contiguous)
    __syncthreads();

    // ---- layer 1a: h = leaky(feat @ W1a + b1a); 2 threads per node ----
    for (int idx = tid; idx < n * 2; idx += BLK) {
        const int i = idx >> 1, half = idx & 1;
        float f0 = feat[(g0 + i) * 3 + 0];
        float f1 = feat[(g0 + i) * 3 + 1];
        float f2 = feat[(g0 + i) * 3 + 2];
        #pragma unroll
        for (int cc = 0; cc < 8; ++cc) {
            const int c0 = half * 64 + cc * 8;
            bf16x8 pk;
            #pragma unroll
            for (int j = 0; j < 8; ++j) {
                const f32x4 w = *(const f32x4*)&wbuf[(c0 + j) * 4];
                pk[j] = (__bf16)leaky(fmaf(f0, w[0], fmaf(f1, w[1], fmaf(f2, w[2], w[3]))));
            }
            *(bf16x8*)(sm + haddr(i, c0 * 2)) = pk;
        }
    }

    const int   ntiles = (n + 15) >> 4;
    const float inv_n  = 1.f / (float)(n > 1 ? n : 1);
    const int   ct0    = cg * 2;
    const int   cnt    = (ntiles > rg) ? ((ntiles - rg + 2) / 3) : 0;  // wave-uniform, <= 13

    // ---- 5 GEMM layers: h = leaky(h @ W + b'), b' = b + mean_prev @ W ----
    for (int L = 0; L < 5; ++L) {
        __syncthreads();                       // h stable (W2 of prev layer), atomics done
        float* csCur  = (L & 1) ? cs1 : cs0;
        float* csPrev = (L & 1) ? cs0 : cs1;
        if (L == 0) {
            if (tid < 128) lbias[tid] = bl0[tid];
        } else {
            // fold residual mean into bias: lbias = b + inv_n * (csPrev @ W), f32
            const float* Wc = (L == 1) ? Wl1 : (L == 2) ? Wl2 : (L == 3) ? Wl3 : Wl4;
            const float* bc = (L == 1) ? bl1 : (L == 2) ? bl2 : (L == 3) ? bl3 : bl4;
            if (tid < 512) {
                const int ch = tid >> 2, q = tid & 3;   // 4 partials of 32 k each
                float sacc = 0.f;
                #pragma unroll 8
                for (int i = 0; i < 32; ++i) {
                    const int k = q * 32 + i;
                    sacc = fmaf(csPrev[k], Wc[k * 128 + ch], sacc);
                }
                sacc += __shfl_xor(sacc, 1);
                sacc += __shfl_xor(sacc, 2);
                if (q == 0) lbias[ch] = fmaf(inv_n, sacc, bc[ch]);
            }
            if (tid < 128) csCur[tid] = 0.f;
        }
        __syncthreads();                       // lbias ready, csCur zeroed

        // A = W^T fragments for this wave's 2 channel tiles (32 VGPR)
        const __bf16* wt = wt5 + L * 16384;
        bf16x8 afrag[2][4];
        #pragma unroll
        for (int c = 0; c < 2; ++c)
            #pragma unroll
            for (int ks = 0; ks < 4; ++ks)
                afrag[c][ks] = *(const bf16x8*)(wt + ((ct0 + c) * 16 + lm) * 128 + ks * 32 + lq * 8);
        f32x4 lbreg[2];
        #pragma unroll
        for (int c = 0; c < 2; ++c)
            lbreg[c] = *(const f32x4*)&lbias[(ct0 + c) * 16 + lq * 4];

        float csum0[4] = {}, csum1[4] = {};
        bf16x4 hreg[JH1][2];

        // ---- phase A1: tiles j=0..6 (rows rt*16, rt = rg+3j <= 20) ----
        #pragma unroll
        for (int j = 0; j < JH1; ++j) {
            if (j < cnt) {
                const int node = (rg + 3 * j) * 16 + lm;
                bf16x8 bfrag[4];
                #pragma unroll
                for (int ks = 0; ks < 4; ++ks)
                    bfrag[ks] = *(const bf16x8*)(sm + haddr(node, ks * 64 + lq * 16));
                f32x4 acc0 = lbreg[0], acc1 = lbreg[1];
                #pragma unroll
                for (int ks = 0; ks < 4; ++ks) {
                    acc0 = __builtin_amdgcn_mfma_f32_16x16x32_bf16(afrag[0][ks], bfrag[ks], acc0, 0, 0, 0);
                    acc1 = __builtin_amdgcn_mfma_f32_16x16x32_bf16(afrag[1][ks], bfrag[ks], acc1, 0, 0, 0);
                }
                #pragma unroll
                for (int i = 0; i < 4; ++i) {
                    hreg[j][0][i] = (__bf16)leaky(acc0[i]);
                    hreg[j][1][i] = (__bf16)leaky(acc1[i]);
                }
            }
            __builtin_amdgcn_sched_barrier(0);  // cap cross-iter hoisting (reg budget)
        }
        __syncthreads();                       // all A1 reads (tiles <= 20) done

        // ---- W1: write tiles 0..6 + csum; then A2: read tiles >= 21 (disjoint) ----
        #pragma unroll
        for (int j = 0; j < JH1; ++j) {
            if (j < cnt) {
                const int node = (rg + 3 * j) * 16 + lm;
                if (node < n) {
                    *(bf16x4*)(sm + haddr(node, (ct0 * 16 + lq * 4) * 2))       = hreg[j][0];
                    *(bf16x4*)(sm + haddr(node, ((ct0 + 1) * 16 + lq * 4) * 2)) = hreg[j][1];
                    #pragma unroll
                    for (int i = 0; i < 4; ++i) {
                        csum0[i] += (float)hreg[j][0][i];
                        csum1[i] += (float)hreg[j][1][i];
                    }
                }
            }
        }
        __builtin_amdgcn_sched_barrier(0);      // W1 emitted before A2 (hreg reuse)
        #pragma unroll
        for (int j = JH1; j < JH1 + JH2; ++j) {
            if (j < cnt) {
                const int node = (rg + 3 * j) * 16 + lm;
                bf16x8 bfrag[4];
                #pragma unroll
                for (int ks = 0; ks < 4; ++ks)
                    bfrag[ks] = *(const bf16x8*)(sm + haddr(node, ks * 64 + lq * 16));
                f32x4 acc0 = lbreg[0], acc1 = lbreg[1];
                #pragma unroll
                for (int ks = 0; ks < 4; ++ks) {
                    acc0 = __builtin_amdgcn_mfma_f32_16x16x32_bf16(afrag[0][ks], bfrag[ks], acc0, 0, 0, 0);
                    acc1 = __builtin_amdgcn_mfma_f32_16x16x32_bf16(afrag[1][ks], bfrag[ks], acc1, 0, 0, 0);
                }
                #pragma unroll
                for (int i = 0; i < 4; ++i) {
                    hreg[j - JH1][0][i] = (__bf16)leaky(acc0[i]);
                    hreg[j - JH1][1][i] = (__bf16)leaky(acc1[i]);
                }
            }
            __builtin_amdgcn_sched_barrier(0);
        }
        __syncthreads();                       // all A2 reads (tiles >= 21) done

        // ---- W2: write tiles 7..12 + finish column sums ----
        #pragma unroll
        for (int j = JH1; j < JH1 + JH2; ++j) {
            if (j < cnt) {
                const int node = (rg + 3 * j) * 16 + lm;
                if (node < n) {
                    *(bf16x4*)(sm + haddr(node, (ct0 * 16 + lq * 4) * 2))       = hreg[j - JH1][0];
                    *(bf16x4*)(sm + haddr(node, ((ct0 + 1) * 16 + lq * 4) * 2)) = hreg[j - JH1][1];
                    #pragma unroll
                    for (int i = 0; i < 4; ++i) {
                        csum0[i] += (float)hreg[j - JH1][0][i];
                        csum1[i] += (float)hreg[j - JH1][1][i];
                    }
                }
            }
        }
        #pragma unroll
        for (int i = 0; i < 4; ++i) {
            float v0 = csum0[i], v1 = csum1[i];
            v0 += __shfl_xor(v0, 1); v0 += __shfl_xor(v0, 2);
            v0 += __shfl_xor(v0, 4); v0 += __shfl_xor(v0, 8);
            v1 += __shfl_xor(v1, 1); v1 += __shfl_xor(v1, 2);
            v1 += __shfl_xor(v1, 4); v1 += __shfl_xor(v1, 8);
            if (lm == 0) {
                atomicAdd(&csCur[ct0 * 16 + lq * 4 + i], v0);
                atomicAdd(&csCur[(ct0 + 1) * 16 + lq * 4 + i], v1);
            }
        }
    }
    __syncthreads();                           // layer-5 atomics into cs0 done

    // ---- output head: g = cs0*inv_n; e = leaky(g@Wo1+bo1)@Wo2 + bo2 ----
    if (wave == 0) {
        float a = bo1[lane];                   // 64 lanes = 64 hidden units
        for (int k = 0; k < 128; ++k)
            a = fmaf(cs0[k] * inv_n, Wo1[k * 64 + lane], a);
        a = leaky(a);
        float e = a * Wo2[lane];
        e += __shfl_xor(e, 32); e += __shfl_xor(e, 16); e += __shfl_xor(e, 8);
        e += __shfl_xor(e, 4);  e += __shfl_xor(e, 2);  e += __shfl_xor(e, 1);
        if (lane == 0) out[s] = e + bo2[0];
    }
}

extern "C" void kernel_launch(void* const* d_in, const int* in_sizes, int n_in,
                              void* d_out, int out_size, void* d_ws, size_t ws_size,
                              hipStream_t stream) {
    (void)in_sizes; (void)n_in; (void)out_size; (void)ws_size;
    const float* feat = (const float*)d_in[0];
    const int*   seg  = (const int*)d_in[1];
    const float* W1a  = (const float*)d_in[2];
    const float* b1a  = (const float*)d_in[3];
    const float* W1b  = (const float*)d_in[4];
    const float* b1b  = (const float*)d_in[5];
    const float* W2   = (const float*)d_in[6];
    const float* b2   = (const float*)d_in[7];
    const float* W3   = (const float*)d_in[8];
    const float* b3   = (const float*)d_in[9];
    const float* W4   = (const float*)d_in[10];
    const float* b4   = (const float*)d_in[11];
    const float* W5   = (const float*)d_in[12];
    const float* b5   = (const float*)d_in[13];
    const float* Wo1  = (const float*)d_in[14];
    const float* bo1  = (const float*)d_in[15];
    const float* Wo2  = (const float*)d_in[16];
    const float* bo2  = (const float*)d_in[17];
    float* out = (float*)d_out;

    __bf16* wt = (__bf16*)d_ws;                                   // 5*16384 bf16
    int* offs = (int*)((char*)d_ws + 5 * 16384 * sizeof(__bf16));

    seg_offsets_kernel<<<(NSEG + 256) / 256, 256, 0, stream>>>(seg, offs);
    wconv_kernel<<<(5 * 16384) / 256, 256, 0, stream>>>(W1b, W2, W3, W4, W5, wt);

    hipFuncSetAttribute((const void*)fused_pflow,
                        hipFuncAttributeMaxDynamicSharedMemorySize, LDS_BYTES);
    fused_pflow<<<NSEG, BLK, LDS_BYTES, stream>>>(feat, offs, wt, W1a, b1a,
                                                  W1b, b1b, W2, b2, W3, b3,
                                                  W4, b4, W5, b5,
                                                  Wo1, bo1, Wo2, bo2, out);
}

// Round 9
// 897.370 us; speedup vs baseline: 1.4735x; 1.2109x over previous
//
#include <hip/hip_runtime.h>
#include <stdint.h>

#define NSEG 2048
#define NTOT 1048576
#define CAP  624            // max nodes per segment held in LDS (multiple of 16)
#define BLK  512
#define H_BYTES (CAP * 256)                      // bf16 h[CAP][128]
// LDS: h | cs[2][128] | lbias[128] | wbuf[512]
#define CS_OFF    H_BYTES
#define LBIAS_OFF (H_BYTES + 1024)
#define WBUF_OFF  (H_BYTES + 1024 + 512)
#define LDS_BYTES (H_BYTES + 1024 + 512 + 2048)  // 163328 <= 163840

typedef __bf16 bf16x8 __attribute__((ext_vector_type(8)));
typedef __bf16 bf16x4 __attribute__((ext_vector_type(4)));
typedef float  f32x4  __attribute__((ext_vector_type(4)));

__device__ __forceinline__ float leaky(float v) { return fmaxf(v, 0.01f * v); }
// swizzled byte address into LDS h tile: row pitch 256B, XOR bits 4-6 by row&7
__device__ __forceinline__ uint32_t haddr(int row, int bytecol) {
    return ((uint32_t)row * 256u + (uint32_t)bytecol) ^ (((uint32_t)row & 7u) << 4);
}

// offs[t] = lower_bound(seg, t): segment t occupies [offs[t], offs[t+1])
__global__ void seg_offsets_kernel(const int* __restrict__ seg, int* __restrict__ offs) {
    int t = blockIdx.x * blockDim.x + threadIdx.x;
    if (t > NSEG) return;
    int lo = 0, hi = NTOT;
    while (lo < hi) { int mid = (lo + hi) >> 1; if (seg[mid] < t) lo = mid + 1; else hi = mid; }
    offs[t] = lo;
}

// Wt[m][n][k] = bf16(W_m[k][n])  (transposed so k is contiguous for fragment loads)
__global__ void wconv_kernel(const float* __restrict__ W1b, const float* __restrict__ W2,
                             const float* __restrict__ W3,  const float* __restrict__ W4,
                             const float* __restrict__ W5,  __bf16* __restrict__ wt) {
    int idx = blockIdx.x * blockDim.x + threadIdx.x;   // 0 .. 5*16384-1
    int m = idx >> 14, e = idx & 16383;
    int nn = e >> 7, kk = e & 127;
    const float* W = (m == 0) ? W1b : (m == 1) ? W2 : (m == 2) ? W3 : (m == 3) ? W4 : W5;
    wt[idx] = (__bf16)W[kk * 128 + nn];
}

extern __shared__ char smem[];

// NOTE: this exact attribute form + 2 waves/EU is the ONLY allocator regime
// that has not spilled (rounds 3-6 evidence). Do not raise waves_per_eu.
__global__ void __attribute__((amdgpu_flat_work_group_size(BLK, BLK),
                               amdgpu_waves_per_eu(2, 2)))
fused_pflow(
    const float* __restrict__ feat, const int* __restrict__ offs,
    const __bf16* __restrict__ wt5,
    const float* __restrict__ W1a, const float* __restrict__ b1a,
    const float* __restrict__ Wl0, const float* __restrict__ bl0,   // W1b,b1b
    const float* __restrict__ Wl1, const float* __restrict__ bl1,   // W2,b2
    const float* __restrict__ Wl2, const float* __restrict__ bl2,
    const float* __restrict__ Wl3, const float* __restrict__ bl3,
    const float* __restrict__ Wl4, const float* __restrict__ bl4,
    const float* __restrict__ Wo1, const float* __restrict__ bo1,
    const float* __restrict__ Wo2, const float* __restrict__ bo2,
    float* __restrict__ out)
{
    const int s    = blockIdx.x;
    const int tid  = threadIdx.x;
    const int lane = tid & 63;
    const int wave = tid >> 6;     // 0..7
    const int lm   = lane & 15;    // MFMA node lane
    const int lq   = lane >> 4;    // C row-quad / k-quad

    char*  sm    = smem;
    float* cs0   = (float*)(sm + CS_OFF);      // column-sum ping
    float* cs1   = cs0 + 128;                  // column-sum pong
    float* lbias = (float*)(sm + LBIAS_OFF);   // folded bias of current layer
    float* wbuf  = (float*)(sm + WBUF_OFF);    // layer-1a W+b, [ch][4]

    const int g0 = offs[s];
    int n = offs[s + 1] - g0;
    n = n < CAP ? n : CAP;

    // wbuf[ch*4+j] = {W1a[0][ch], W1a[1][ch], W1a[2][ch], b1a[ch]}
    for (int i = tid; i < 512; i += BLK) {
        int ch = i >> 2, j = i & 3;
        wbuf[i] = (j < 3) ? W1a[j * 128 + ch] : b1a[ch];
    }
    if (tid < 256) cs0[tid] = 0.f;             // zero both cs buffers (contiguous)
    __syncthreads();

    // ---- layer 1a: h = leaky(feat @ W1a + b1a), fp32 VALU (K=3) ----
    for (int i = tid; i < n; i += BLK) {
        float f0 = feat[(g0 + i) * 3 + 0];
        float f1 = feat[(g0 + i) * 3 + 1];
        float f2 = feat[(g0 + i) * 3 + 2];
        #pragma unroll
        for (int c0 = 0; c0 < 128; c0 += 8) {
            bf16x8 pk;
            #pragma unroll
            for (int j = 0; j < 8; ++j) {
                const f32x4 w = *(const f32x4*)&wbuf[(c0 + j) * 4];
                pk[j] = (__bf16)leaky(fmaf(f0, w[0], fmaf(f1, w[1], fmaf(f2, w[2], w[3]))));
            }
            *(bf16x8*)(sm + haddr(i, c0 * 2)) = pk;
        }
    }

    const int   ntiles = (n + 15) >> 4;
    const float inv_n  = 1.f / (float)(n > 1 ? n : 1);

    // ---- 5 GEMM layers: h = leaky(h @ W + b'), b' = b + mean_prev @ W ----
    for (int L = 0; L < 5; ++L) {
        __syncthreads();                       // h stable, prev-layer atomics done
        float* csCur  = (L & 1) ? cs1 : cs0;
        float* csPrev = (L & 1) ? cs0 : cs1;
        if (L == 0) {
            if (tid < 128) lbias[tid] = bl0[tid];
        } else {
            // fold residual mean into bias: lbias = b + inv_n * (csPrev @ W), f32
            const float* Wc = (L == 1) ? Wl1 : (L == 2) ? Wl2 : (L == 3) ? Wl3 : Wl4;
            const float* bc = (L == 1) ? bl1 : (L == 2) ? bl2 : (L == 3) ? bl3 : bl4;
            const int ch = tid >> 2, q = tid & 3;
            float sacc = 0.f;
            #pragma unroll 8
            for (int i = 0; i < 32; ++i) {
                const int k = q * 32 + i;
                sacc = fmaf(csPrev[k], Wc[k * 128 + ch], sacc);
            }
            sacc += __shfl_xor(sacc, 1);
            sacc += __shfl_xor(sacc, 2);
            if (q == 0) lbias[ch] = fmaf(inv_n, sacc, bc[ch]);
            if (tid < 128) csCur[tid] = 0.f;
        }
        __syncthreads();                       // lbias ready, csCur zeroed

        // A = W^T fragments, whole 128x128 W register-resident
        const __bf16* wt = wt5 + L * 16384;
        bf16x8 afrag[8][4];
        #pragma unroll
        for (int ct = 0; ct < 8; ++ct)
            #pragma unroll
            for (int ks = 0; ks < 4; ++ks)
                afrag[ct][ks] = *(const bf16x8*)(wt + (ct * 16 + lm) * 128 + ks * 32 + lq * 8);

        float creg[8][4] = {};                 // column-sum partials

        // ---- software-pipelined tile loop: prefetch bfrag of tile rt+8 ----
        bf16x8 bfA[4];                         // current tile's B fragments
        if (wave < ntiles) {
            const int node0 = wave * 16 + lm;
            #pragma unroll
            for (int ks = 0; ks < 4; ++ks)
                bfA[ks] = *(const bf16x8*)(sm + haddr(node0, ks * 64 + lq * 16));
        }
        for (int rt = wave; rt < ntiles; rt += 8) {
            // acc-init reads FIRST (LDS retires in order: waiting on these
            // leaves the later prefetch reads outstanding through the MFMAs)
            f32x4 acc[8];
            #pragma unroll
            for (int ct = 0; ct < 8; ++ct)
                acc[ct] = *(const f32x4*)&lbias[ct * 16 + lq * 4];
            // prefetch next tile's B fragments (this wave owns tile rt+8 too)
            bf16x8 bfB[4];
            const int rtn = rt + 8;
            if (rtn < ntiles) {
                const int noden = rtn * 16 + lm;
                #pragma unroll
                for (int ks = 0; ks < 4; ++ks)
                    bfB[ks] = *(const bf16x8*)(sm + haddr(noden, ks * 64 + lq * 16));
            }
            // MFMAs on current tile (bfA already in regs)
            #pragma unroll
            for (int ks = 0; ks < 4; ++ks)
                #pragma unroll
                for (int ct = 0; ct < 8; ++ct)
                    acc[ct] = __builtin_amdgcn_mfma_f32_16x16x32_bf16(afrag[ct][ks], bfA[ks], acc[ct], 0, 0, 0);
            // epilogue: leaky, column-sum, pack, write back in place
            const int node = rt * 16 + lm;
            if (node < n) {
                #pragma unroll
                for (int ct = 0; ct < 8; ++ct) {
                    bf16x4 pk;
                    #pragma unroll
                    for (int i = 0; i < 4; ++i) {
                        float v = leaky(acc[ct][i]);
                        creg[ct][i] += v;
                        pk[i] = (__bf16)v;     // compiler emits v_cvt_pk_bf16_f32
                    }
                    *(bf16x4*)(sm + haddr(node, (ct * 16 + lq * 4) * 2)) = pk;
                }
            }
            // rotate prefetched fragments into place
            #pragma unroll
            for (int ks = 0; ks < 4; ++ks) bfA[ks] = bfB[ks];
        }
        // reduce column-sum partials over the 16 node-lanes, one atomic per channel
        #pragma unroll
        for (int ct = 0; ct < 8; ++ct)
            #pragma unroll
            for (int i = 0; i < 4; ++i) {
                float v = creg[ct][i];
                v += __shfl_xor(v, 1); v += __shfl_xor(v, 2);
                v += __shfl_xor(v, 4); v += __shfl_xor(v, 8);
                if (lm == 0) atomicAdd(&csCur[ct * 16 + lq * 4 + i], v);
            }
    }
    __syncthreads();                           // layer-5 atomics into cs0 done

    // ---- output head: g = cs0*inv_n; e = leaky(g@Wo1+bo1)@Wo2 + bo2 ----
    if (wave == 0) {
        float a = bo1[lane];                   // 64 lanes = 64 hidden units
        for (int k = 0; k < 128; ++k)
            a = fmaf(cs0[k] * inv_n, Wo1[k * 64 + lane], a);
        a = leaky(a);
        float e = a * Wo2[lane];
        e += __shfl_xor(e, 32); e += __shfl_xor(e, 16); e += __shfl_xor(e, 8);
        e += __shfl_xor(e, 4);  e += __shfl_xor(e, 2);  e += __shfl_xor(e, 1);
        if (lane == 0) out[s] = e + bo2[0];
    }
}

extern "C" void kernel_launch(void* const* d_in, const int* in_sizes, int n_in,
                              void* d_out, int out_size, void* d_ws, size_t ws_size,
                              hipStream_t stream) {
    (void)in_sizes; (void)n_in; (void)out_size; (void)ws_size;
    const float* feat = (const float*)d_in[0];
    const int*   seg  = (const int*)d_in[1];
    const float* W1a  = (const float*)d_in[2];
    const float* b1a  = (const float*)d_in[3];
    const float* W1b  = (const float*)d_in[4];
    const float* b1b  = (const float*)d_in[5];
    const float* W2   = (const float*)d_in[6];
    const float* b2   = (const float*)d_in[7];
    const float* W3   = (const float*)d_in[8];
    const float* b3   = (const float*)d_in[9];
    const float* W4   = (const float*)d_in[10];
    const float* b4   = (const float*)d_in[11];
    const float* W5   = (const float*)d_in[12];
    const float* b5   = (const float*)d_in[13];
    const float* Wo1  = (const float*)d_in[14];
    const float* bo1  = (const float*)d_in[15];
    const float* Wo2  = (const float*)d_in[16];
    const float* bo2  = (const float*)d_in[17];
    float* out = (float*)d_out;

    __bf16* wt = (__bf16*)d_ws;                                   // 5*16384 bf16
    int* offs = (int*)((char*)d_ws + 5 * 16384 * sizeof(__bf16));

    seg_offsets_kernel<<<(NSEG + 256) / 256, 256, 0, stream>>>(seg, offs);
    wconv_kernel<<<(5 * 16384) / 256, 256, 0, stream>>>(W1b, W2, W3, W4, W5, wt);

    hipFuncSetAttribute((const void*)fused_pflow,
                        hipFuncAttributeMaxDynamicSharedMemorySize, LDS_BYTES);
    fused_pflow<<<NSEG, BLK, LDS_BYTES, stream>>>(feat, offs, wt, W1a, b1a,
                                                  W1b, b1b, W2, b2, W3, b3,
                                                  W4, b4, W5, b5,
                                                  Wo1, bo1, Wo2, bo2, out);
}